// Round 12
// baseline (53.603 us; speedup 1.0000x reference)
//
#include <hip/hip_runtime.h>
#include <cstddef>

typedef __attribute__((ext_vector_type(8))) short short8v;
typedef __attribute__((ext_vector_type(4))) short short4v;
typedef __attribute__((ext_vector_type(4))) float f32x4;

__device__ __forceinline__ unsigned short f2bf(float f) {
    unsigned u = __float_as_uint(f);
    u = (u + 0x7FFFu + ((u >> 16) & 1u)) >> 16;
    return (unsigned short)u;
}

// ---- prep (verified R4/R6/R10): W[o][d][e][w] fp32 -> Wb frag-stream bf16 ----
// Wb[(g*64+f)*36864 + ks*2048 + nt*512 + lane*8 + j], ks = e*9 + w9
//   = bf16( W[o = g*64+nt*16+(lane&15), d = (lane>>4)*8+j, e = 2f+e, w = w9] )
__global__ __launch_bounds__(256) void prep_w(const float* __restrict__ w,
                                              unsigned short* __restrict__ wb)
{
    const int g  = blockIdx.x >> 6;
    const int f  = blockIdx.x & 63;
    const int e0 = 2 * f;
    const int tid = threadIdx.x;
    __shared__ unsigned short ls[64 * 580];   // pitch 580 breaks power-of-2 banks

    #pragma unroll 4
    for (int i = 0; i < 72; ++i) {
        int fl  = tid + i * 256;           // (o_l,d) x 9 float2
        int od  = fl / 9;
        int f2i = fl - od * 9;
        int o_l = od >> 5;
        int d   = od & 31;
        const float2 v = *reinterpret_cast<const float2*>(
            &w[(size_t)((g * 64 + o_l) * 32 + d) * 1152 + e0 * 9 + f2i * 2]);
        ushort2 hh; hh.x = f2bf(v.x); hh.y = f2bf(v.y);
        *reinterpret_cast<ushort2*>(&ls[o_l * 580 + d * 18 + f2i * 2]) = hh;
    }
    __syncthreads();

    unsigned short* wo = wb + (size_t)(g * 64 + f) * 36864;
    #pragma unroll 2
    for (int i = 0; i < 18; ++i) {
        int oc   = tid + i * 256;          // (ks, nt, lane)
        int ks   = oc >> 8;
        int nt   = (oc >> 6) & 3;
        int lane = oc & 63;
        int li = lane & 15, hi = lane >> 4;
        int e  = (ks >= 9) ? 1 : 0;
        int w9 = ks - 9 * e;
        int o_l = nt * 16 + li;
        short8v vv;
        #pragma unroll
        for (int j = 0; j < 8; ++j)
            vv[j] = (short)ls[o_l * 580 + (hi * 8 + j) * 18 + e * 9 + w9];
        *reinterpret_cast<short8v*>(&wo[(size_t)oc * 8]) = vv;
    }
}

// ---- main: block = (g,f), 512 threads = 8 waves: 4 PRODUCERS (stream x ->
// double-buffered LDS slabs) + 4 CONSUMERS (LDS -> MFMA -> store). Producer
// vmcnt drains overlap consumer compute: memory stays busy continuously.
// LDS 160768 B = As 73728 + 4 x-slabs (2 sets x 2 batches) x 21760.
__global__ __launch_bounds__(512, 1) void lconv_mfma(const float* __restrict__ x,
                                                     const unsigned short* __restrict__ wb,
                                                     float* __restrict__ out)
{
    extern __shared__ __align__(16) unsigned short smem[];
    unsigned short* As = smem;                 // 36864 shorts
    unsigned short* xs = smem + 36864;         // set*21760 + blz*10880 + e*5440 + tp*40 + d

    const int g  = blockIdx.x >> 6;
    const int f  = blockIdx.x & 63;
    const int e0 = 2 * f;

    const int tid  = threadIdx.x;
    const int lane = tid & 63;
    const int wv   = tid >> 6;          // 0..3 consumers, 4..7 producers
    const int li   = lane & 15;
    const int hi   = lane >> 4;

    // ---- A: async global->LDS, linear, all 512 threads ----
    const unsigned short* wslab = wb + (size_t)(g * 64 + f) * 36864;
    #pragma unroll
    for (int i = 0; i < 9; ++i) {
        __builtin_amdgcn_global_load_lds(
            (const __attribute__((address_space(1))) void*)(wslab + i * 4096 + tid * 8),
            (__attribute__((address_space(3))) void*)(As + i * 4096 + tid * 8),
            16, 0, 0);
    }

    // ---- zero pads: 4 slabs x 2 e x {tp 0..3,132..135} x 40 d = 640 quads ----
    #pragma unroll
    for (int it = 0; it < 2; ++it) {
        int u = it * 512 + tid;
        if (u < 640) {
            int slab = u / 160;
            int rem  = u % 160;
            int e    = rem / 80;
            int r    = (rem % 80) / 10;
            int dq   = rem % 10;
            int tp   = (r < 4) ? r : (128 + r);
            short4v zz = {0, 0, 0, 0};
            *reinterpret_cast<short4v*>(
                &xs[slab * 10880 + e * 5440 + tp * 40 + dq * 4]) = zz;
        }
    }

    // ================= PRODUCER waves (wv 4..7) =================
    const int blz = wv & 1;         // batch within pair
    const int pe  = (wv >> 1) & 1;  // e half   (for wv>=4: (wv-4)>>1 == (wv>>1)&1)
    float2 fr[32];

    auto pstage = [&](int pair, int set) {
        const int b = pair * 2 + blz;
        const float* xp0 = &x[((size_t)(b * 128 + g * 32) * 128 + (e0 + pe)) * 128 + 2 * lane];
        #pragma unroll
        for (int d = 0; d < 32; ++d)
            fr[d] = *reinterpret_cast<const float2*>(xp0 + (size_t)d * 16384);
        unsigned short* base = xs + set * 21760 + blz * 10880 + pe * 5440 + (2 * lane + 4) * 40;
        #pragma unroll
        for (int dq = 0; dq < 8; ++dq) {
            short4v h0, h1;
            #pragma unroll
            for (int j = 0; j < 4; ++j) {
                h0[j] = (short)f2bf(fr[dq * 4 + j].x);
                h1[j] = (short)f2bf(fr[dq * 4 + j].y);
            }
            *reinterpret_cast<short4v*>(&base[dq * 4])      = h0;
            *reinterpret_cast<short4v*>(&base[40 + dq * 4]) = h1;
        }
    };

    // ================= CONSUMER waves (wv 0..3) =================
    const int bl = wv & 1;          // batch within pair
    const int th = wv >> 1;         // t-half
    f32x4 acc[4][4];
    #pragma unroll
    for (int nt = 0; nt < 4; ++nt)
        #pragma unroll
        for (int tt = 0; tt < 4; ++tt)
            acc[nt][tt] = (f32x4){0.f, 0.f, 0.f, 0.f};

    auto compute_pair = [&](int pair, int set) {
        const unsigned short* xb = xs + set * 21760 + bl * 10880;
        #pragma unroll
        for (int e = 0; e < 2; ++e) {
            #pragma unroll
            for (int w9 = 0; w9 < 9; ++w9) {
                short8v Af[4], Bf[4];
                #pragma unroll
                for (int nt = 0; nt < 4; ++nt)   // lane-linear: conflict-free
                    Af[nt] = *reinterpret_cast<const short8v*>(
                        &As[(e * 9 + w9) * 2048 + nt * 512 + lane * 8]);
                #pragma unroll
                for (int tt = 0; tt < 4; ++tt) {
                    int tp = th * 64 + tt * 16 + li + w9;
                    Bf[tt] = *reinterpret_cast<const short8v*>(
                        &xb[e * 5440 + tp * 40 + hi * 8]);
                }
                __builtin_amdgcn_s_setprio(1);
                #pragma unroll
                for (int nt = 0; nt < 4; ++nt)
                    #pragma unroll
                    for (int tt = 0; tt < 4; ++tt)
                        acc[nt][tt] = __builtin_amdgcn_mfma_f32_16x16x32_bf16(
                            Af[nt], Bf[tt], acc[nt][tt], 0, 0, 0);
                __builtin_amdgcn_s_setprio(0);
            }
        }
        // store + reset acc
        const int b = pair * 2 + bl;
        #pragma unroll
        for (int nt = 0; nt < 4; ++nt)
            #pragma unroll
            for (int tt = 0; tt < 4; ++tt)
                #pragma unroll
                for (int j = 0; j < 4; ++j) {
                    float v = acc[nt][tt][j];
                    v = (v >= 0.f) ? v : 0.01f * v;
                    int n  = nt * 16 + hi * 4 + j;
                    int tc = th * 64 + tt * 16 + li;
                    out[(((size_t)(b * 256 + g * 64 + n)) * 64 + f) * 128 + tc] = v;
                    acc[nt][tt][j] = 0.f;
                }
    };

    // ================= pipeline =================
    if (wv >= 4) pstage(0, 0);
    __syncthreads();                  // A + pair0 + pads ready

    for (int p = 0; p < 4; ++p) {
        if (wv < 4) {
            compute_pair(p, p & 1);
        } else if (p < 3) {
            pstage(p + 1, (p + 1) & 1);
        }
        __syncthreads();              // producer drain overlaps consumer compute
    }
}

extern "C" void kernel_launch(void* const* d_in, const int* in_sizes, int n_in,
                              void* d_out, int out_size, void* d_ws, size_t ws_size,
                              hipStream_t stream)
{
    const float* x = (const float*)d_in[0];           // (8,128,128,128) fp32
    const float* w = (const float*)d_in[1];           // (256,32,128,9) fp32
    float* out = (float*)d_out;                       // (8,256,64,128) fp32
    unsigned short* wb = (unsigned short*)d_ws;       // 256*36864 bf16 = 18.9 MB

    (void)hipFuncSetAttribute((const void*)lconv_mfma,
                              hipFuncAttributeMaxDynamicSharedMemorySize, 160768);

    hipLaunchKernelGGL(prep_w, dim3(256), dim3(256), 0, stream, w, wb);
    hipLaunchKernelGGL(lconv_mfma, dim3(256), dim3(512), 160768, stream, x, wb, out);
}